// Round 11
// baseline (145.623 us; speedup 1.0000x reference)
//
#include <hip/hip_runtime.h>
#include <math.h>

// Match numpy (no FMA contraction) — mask boundary is bit-sensitive.
#pragma clang fp contract(off)

namespace {

constexpr int B = 12, H = 192, W = 640;
constexpr int HW  = H * W;        // 122880
constexpr int BHW = B * HW;       // 1474560
constexpr float EPS = 1e-7f;

constexpr int TR    = 24;         // target-tile rows per winner block
constexpr int TILES = H / TR;     // 8 tiles/batch
constexpr int TRW   = TR * W;     // 15360 targets per tile
constexpr int SC    = 4;          // source chunks per tile (u16 local keys)
constexpr int HWC   = HW / SC;    // 30720 (< 2^16)
constexpr int NBLK  = B * TILES * SC;  // 384 winner blocks
constexpr int SPB   = HW / (TILES * SC); // 3840 static-pass pixels per block
constexpr int WTPB  = 1024;

constexpr int FBLK  = 256;        // k_final grid: <= 1 block/CU guaranteed at
constexpr int FTPB  = 1024;       // launch_bounds(1024,4) -> all co-resident.

// ws: redA[NBLK*4] f32 @ +0 | redB[FBLK*2] f32 @ +8192 | bar u32 @ +12288 |
//     partial[NBLK*TRW] u16 @ +16384  (11.8 MB proven footprint)
// check[] scratch lives in out[0..BHW) within k_final (same-thread stash).

__device__ __forceinline__ void computeP(const float* __restrict__ Kb,
                                         const float* __restrict__ Po, float* P) {
#pragma unroll
    for (int i = 0; i < 3; ++i)
#pragma unroll
        for (int j = 0; j < 4; ++j) {
            float s = Kb[i*4+0] * Po[0*4+j];
            s = s + Kb[i*4+1] * Po[1*4+j];
            s = s + Kb[i*4+2] * Po[2*4+j];
            s = s + Kb[i*4+3] * Po[3*4+j];
            P[i*4+j] = s;
        }
}

__device__ __forceinline__ void static_flow_P(
    const float* __restrict__ iK, const float* __restrict__ P,
    int x, int y, float d, float& sx, float& sy)
{
    float fx = (float)x, fy = (float)y;
    float cam0 = iK[0]*fx + iK[1]*fy + iK[2];
    float cam1 = iK[4]*fx + iK[5]*fy + iK[6];
    float cam2 = iK[8]*fx + iK[9]*fy + iK[10];
    cam0 = d * cam0; cam1 = d * cam1; cam2 = d * cam2;
    float cp0 = P[0]*cam0 + P[1]*cam1 + P[2]*cam2  + P[3];
    float cp1 = P[4]*cam0 + P[5]*cam1 + P[6]*cam2  + P[7];
    float cp2 = P[8]*cam0 + P[9]*cam1 + P[10]*cam2 + P[11];
    float pz = cp2 + EPS;
    sx = cp0 / pz - fx;
    sy = cp1 / pz - fy;
}

__device__ __forceinline__ float norm01(float v, float mn, float mx) {
    return (2.0f * (v - mn)) / (mx - mn) - 1.0f;
}

__device__ __forceinline__ void blockRed4(float& a0, float& a1, float& a2, float& a3,
                                          float (*sred)[4], float* bc) {
    for (int off = 32; off; off >>= 1) {
        a0 = fminf(a0, __shfl_down(a0, off, 64));
        a1 = fmaxf(a1, __shfl_down(a1, off, 64));
        a2 = fminf(a2, __shfl_down(a2, off, 64));
        a3 = fmaxf(a3, __shfl_down(a3, off, 64));
    }
    int lane = threadIdx.x & 63, wv = threadIdx.x >> 6;
    if (lane == 0) { sred[wv][0]=a0; sred[wv][1]=a1; sred[wv][2]=a2; sred[wv][3]=a3; }
    __syncthreads();
    if (threadIdx.x == 0) {
#pragma unroll
        for (int w = 1; w < 16; ++w) {
            a0 = fminf(a0, sred[w][0]); a1 = fmaxf(a1, sred[w][1]);
            a2 = fminf(a2, sred[w][2]); a3 = fmaxf(a3, sred[w][3]);
        }
        bc[0]=a0; bc[1]=a1; bc[2]=a2; bc[3]=a3;
    }
    __syncthreads();
    a0=bc[0]; a1=bc[1]; a2=bc[2]; a3=bc[3];
}

__device__ __forceinline__ void blockRed2(float& a0, float& a1,
                                          float (*sred)[4], float* bc) {
    for (int off = 32; off; off >>= 1) {
        a0 = fminf(a0, __shfl_down(a0, off, 64));
        a1 = fmaxf(a1, __shfl_down(a1, off, 64));
    }
    int lane = threadIdx.x & 63, wv = threadIdx.x >> 6;
    if (lane == 0) { sred[wv][0]=a0; sred[wv][1]=a1; }
    __syncthreads();
    if (threadIdx.x == 0) {
#pragma unroll
        for (int w = 1; w < 16; ++w) {
            a0 = fminf(a0, sred[w][0]); a1 = fmaxf(a1, sred[w][1]);
        }
        bc[0]=a0; bc[1]=a1;
    }
    __syncthreads();
    a0=bc[0]; a1=bc[1];
}

// Dispatch 1: winner scan (LDS atomics, chunk-local u16 keys) + flow min/max
// free on the same loads + 1/384 slice of static-flow min/max. Block 0 also
// zeroes the k_final barrier counter (dispatch boundary -> visible).
__global__ void __launch_bounds__(WTPB, 8)
k_winner(const float* __restrict__ flow, const float* __restrict__ depth,
         const float* __restrict__ Km, const float* __restrict__ invK,
         const float* __restrict__ pose,
         unsigned short* __restrict__ partial, float* __restrict__ redA,
         unsigned int* __restrict__ bar) {
    if (blockIdx.x == 0 && threadIdx.x == 0) *bar = 0u;
    __shared__ unsigned int win[TRW];   // 61440 B -> 2 blocks/CU
    __shared__ float sred[16][4];
    __shared__ float bc[4];

    const int wg    = blockIdx.x;
    const int chunk = wg & (SC - 1);
    const int bt    = wg >> 2;
    const int b     = bt / TILES;
    const int tile  = bt - b * TILES;
    const int t0    = tile * TR;

    const float* fx_p = flow + b * 2 * HW;
    const float* fy_p = fx_p + HW;

    for (int i = threadIdx.x; i < TRW; i += WTPB) win[i] = 0u;
    __syncthreads();

    float fmn = INFINITY, fmx = -INFINITY, smn = INFINITY, smx = -INFINITY;
    const int s_beg = chunk * HWC;
    const int s_end = s_beg + HWC;
    for (int s0 = s_beg + threadIdx.x * 4; s0 < s_end; s0 += WTPB * 4) {
        float4 fx4 = *(const float4*)(fx_p + s0);
        float4 fy4 = *(const float4*)(fy_p + s0);
        fmn = fminf(fmn, fminf(fminf(fx4.x, fx4.y), fminf(fx4.z, fx4.w)));
        fmx = fmaxf(fmx, fmaxf(fmaxf(fx4.x, fx4.y), fmaxf(fx4.z, fx4.w)));
        fmn = fminf(fmn, fminf(fminf(fy4.x, fy4.y), fminf(fy4.z, fy4.w)));
        fmx = fmaxf(fmx, fmaxf(fmaxf(fy4.x, fy4.y), fmaxf(fy4.z, fy4.w)));
        int y = s0 / W;
        int x = s0 - y * W;              // groups never cross a row (W%4==0)
        float fxa[4] = {fx4.x, fx4.y, fx4.z, fx4.w};
        float fya[4] = {fy4.x, fy4.y, fy4.z, fy4.w};
#pragma unroll
        for (int j = 0; j < 4; ++j) {
            int cxi = (int)rintf((float)(x + j) + fxa[j]);
            int cyi = (int)rintf((float)y + fya[j]);
            cxi = min(max(cxi, 0), W - 1);
            cyi = min(max(cyi, 0), H - 1);
            if (cyi >= t0 && cyi < t0 + TR) {
                unsigned key = (unsigned)(s0 + j + 1 - s_beg);  // local, <=30720
                atomicMax(&win[(cyi - t0) * W + cxi], key);
            }
        }
    }
    __syncthreads();
    {   // partial writeout (coalesced u16)
        unsigned short* dst = partial + (size_t)wg * TRW;
        for (int i = threadIdx.x; i < TRW; i += WTPB)
            dst[i] = (unsigned short)win[i];
    }

    {   // static-flow min/max over this block's distinct 3840-pixel slice
        const float* iK = invK + b * 16;
        float P[12];
        computeP(Km + b * 16, pose + b * 16, P);
        int n0s = chunk * HWC + tile * SPB;
        if (threadIdx.x < SPB / 4) {
            int n = n0s + threadIdx.x * 4;
            int y = n / W;
            int x0 = n - y * W;
            float4 d4 = *(const float4*)(depth + b * HW + n);
            float da[4] = {d4.x, d4.y, d4.z, d4.w};
#pragma unroll
            for (int j = 0; j < 4; ++j) {
                float sx, sy;
                static_flow_P(iK, P, x0 + j, y, da[j], sx, sy);
                smn = fminf(smn, fminf(sx, sy));
                smx = fmaxf(smx, fmaxf(sx, sy));
            }
        }
    }
    blockRed4(fmn, fmx, smn, smx, sred, bc);
    if (threadIdx.x == 0) {
        redA[wg*4+0] = fmn; redA[wg*4+1] = fmx;
        redA[wg*4+2] = smn; redA[wg*4+3] = smx;
    }
}

// Dispatch 2: redA reduce + check pass (stash in out's mask region) + redB
// partial + scalar barrier (2 KB post-barrier reads only) + winner merge /
// exact payload (overlaps barrier wait) + threshold stash in place.
__global__ void __launch_bounds__(FTPB, 4)
k_final(const float* __restrict__ flow, const float* __restrict__ depth,
        const int* __restrict__ seg,
        const float* __restrict__ Km, const float* __restrict__ invK,
        const float* __restrict__ pose,
        const float* __restrict__ redA, float* __restrict__ redB,
        const unsigned short* __restrict__ partial,
        unsigned int* __restrict__ bar, float* __restrict__ out) {
    __shared__ float sred[16][4];
    __shared__ float bc[4];

    // 1. global flow/static min/max from redA partials (L2-hit)
    float gfmn = INFINITY, gfmx = -INFINITY, gsmn = INFINITY, gsmx = -INFINITY;
    for (int i = threadIdx.x; i < NBLK; i += FTPB) {
        gfmn = fminf(gfmn, redA[i*4+0]); gfmx = fmaxf(gfmx, redA[i*4+1]);
        gsmn = fminf(gsmn, redA[i*4+2]); gsmx = fmaxf(gsmx, redA[i*4+3]);
    }
    blockRed4(gfmn, gfmx, gsmn, gsmx, sred, bc);

    // 2. check pass; stash to out[0..BHW) (same thread re-reads it later)
    float cmn = INFINITY, cmx = -INFINITY;
    int bCur = -1;
    float P[12];
    const int stride = FBLK * FTPB;
    for (int g = blockIdx.x * blockDim.x + threadIdx.x; g < BHW / 4; g += stride) {
        int p0 = g * 4;
        int b  = p0 / HW;
        if (b != bCur) { computeP(Km + b * 16, pose + b * 16, P); bCur = b; }
        const float* iK = invK + b * 16;
        int n0 = p0 - b * HW;
        int y  = n0 / W;
        int x0 = n0 - y * W;
        float4 fx4 = *(const float4*)(flow + b*2*HW + n0);
        float4 fy4 = *(const float4*)(flow + b*2*HW + HW + n0);
        float4 d4  = *(const float4*)(depth + p0);
        float fxa[4] = {fx4.x, fx4.y, fx4.z, fx4.w};
        float fya[4] = {fy4.x, fy4.y, fy4.z, fy4.w};
        float da[4]  = {d4.x, d4.y, d4.z, d4.w};
        float4 cv;
        float* cva = (float*)&cv;
#pragma unroll
        for (int j = 0; j < 4; ++j) {
            float sx, sy;
            static_flow_P(iK, P, x0 + j, y, da[j], sx, sy);
            float dx = norm01(fxa[j], gfmn, gfmx) - norm01(sx, gsmn, gsmx);
            float dy = norm01(fya[j], gfmn, gfmx) - norm01(sy, gsmn, gsmx);
            float c = sqrtf(dx*dx + dy*dy);
            cva[j] = c;
            cmn = fminf(cmn, c); cmx = fmaxf(cmx, c);
        }
        *(float4*)(out + p0) = cv;
    }
    blockRed2(cmn, cmx, sred, bc);
    if (threadIdx.x == 0) {
        // coherence-point stores (bypass stale L1/L2 from harness fill)
        __hip_atomic_store(&redB[blockIdx.x*2],   cmn, __ATOMIC_RELAXED,
                           __HIP_MEMORY_SCOPE_AGENT);
        __hip_atomic_store(&redB[blockIdx.x*2+1], cmx, __ATOMIC_RELAXED,
                           __HIP_MEMORY_SCOPE_AGENT);
        __threadfence();                 // release redB
        atomicAdd(bar, 1u);              // arrive
    }

    // 3. winner merge + exact payload — independent of barrier; hides wait
    for (int p = blockIdx.x * blockDim.x + threadIdx.x; p < BHW; p += stride) {
        int b    = p / HW;
        int n    = p - b * HW;
        int tile = n / TRW;
        int off  = n - tile * TRW;
        const unsigned short* base =
            partial + (size_t)(b * TILES + tile) * SC * TRW + off;
        int nw = -1;
#pragma unroll
        for (int cch = 0; cch < SC; ++cch) {
            unsigned k = base[(size_t)cch * TRW];
            if (k) nw = cch * HWC + (int)k - 1;   // highest nonzero chunk wins
        }
        float bx = 0.0f, by = 0.0f, sg = 0.0f;
        if (nw >= 0) {
            bx = -flow[b*2*HW + nw];
            by = -flow[b*2*HW + HW + nw];
            sg = seg[b*HW + nw] ? 1.0f : 0.0f;
        }
        out[BHW + b*2*HW + n]      = bx;
        out[BHW + b*2*HW + HW + n] = by;
        out[3*BHW + p]             = sg;
    }

    // 4. scalar barrier: spin on counter, then reduce redB (2 KB atomics)
    if (threadIdx.x == 0) {
        while (__hip_atomic_load(bar, __ATOMIC_ACQUIRE,
                                 __HIP_MEMORY_SCOPE_AGENT) < (unsigned)FBLK)
            __builtin_amdgcn_s_sleep(1);
    }
    __syncthreads();

    float gcmn = INFINITY, gcmx = -INFINITY;
    if (threadIdx.x < FBLK) {
        gcmn = __hip_atomic_load(&redB[threadIdx.x*2],   __ATOMIC_RELAXED,
                                 __HIP_MEMORY_SCOPE_AGENT);
        gcmx = __hip_atomic_load(&redB[threadIdx.x*2+1], __ATOMIC_RELAXED,
                                 __HIP_MEMORY_SCOPE_AGENT);
    }
    blockRed2(gcmn, gcmx, sred, bc);

    // 5. threshold stash in place (same-thread same-address -> cache hit)
    for (int p = blockIdx.x * blockDim.x + threadIdx.x; p < BHW; p += stride) {
        float c  = out[p];
        float cn = (c - gcmn) / (gcmx - gcmn);
        out[p] = (cn < 0.98f) ? 1.0f : 0.0f;
    }
}

} // namespace

extern "C" void kernel_launch(void* const* d_in, const int* in_sizes, int n_in,
                              void* d_out, int out_size, void* d_ws, size_t ws_size,
                              hipStream_t stream) {
    const float* flow  = (const float*)d_in[0];
    const float* depth = (const float*)d_in[1];
    const float* Km    = (const float*)d_in[2];
    const float* invK  = (const float*)d_in[3];
    const float* pose  = (const float*)d_in[4];
    const int*   seg   = (const int*)d_in[5];
    float* out = (float*)d_out;

    float* redA = (float*)d_ws;
    float* redB = (float*)((char*)d_ws + 8192);
    unsigned int* bar = (unsigned int*)((char*)d_ws + 12288);
    unsigned short* partial = (unsigned short*)((char*)d_ws + 16384);  // 11.8 MB

    k_winner<<<NBLK, WTPB, 0, stream>>>(flow, depth, Km, invK, pose,
                                        partial, redA, bar);
    k_final <<<FBLK, FTPB, 0, stream>>>(flow, depth, seg, Km, invK, pose,
                                        redA, redB, partial, bar, out);
}

// Round 14
// 139.809 us; speedup vs baseline: 1.0416x; 1.0416x over previous
//
#include <hip/hip_runtime.h>
#include <math.h>

// Match numpy (no FMA contraction) — mask boundary is bit-sensitive.
#pragma clang fp contract(off)

namespace {

constexpr int B = 12, H = 192, W = 640;
constexpr int HW  = H * W;        // 122880
constexpr int BHW = B * HW;       // 1474560
constexpr float EPS = 1e-7f;

constexpr int TR    = 24;         // target-tile rows per winner block
constexpr int TILES = H / TR;     // 8 tiles/batch  (scan traffic ∝ TILES)
constexpr int TRW   = TR * W;     // 15360 targets per tile
constexpr int SC    = 4;          // source chunks per tile (merge ∝ SC, u16)
constexpr int HWC   = HW / SC;    // 30720 sources per chunk (< 2^16)
constexpr int NBLK  = B * TILES * SC;  // 384 winner blocks
constexpr int SPB   = HW / (TILES * SC); // 3840 static-pass pixels per block
constexpr int WTPB  = 1024;
constexpr int RBLK  = 256;        // R10-proven launch config (512 source failed
constexpr int RTPB  = 1024;       // twice at the broker — reverted for A/B)

// ws: redA[NBLK*4] f32 @ +0 | redB[RBLK*2] f32 @ +8192 |
//     partial[NBLK*TRW] u16 @ +16384  (11.8 MB — proven footprint)
// check[] scratch lives in out[0..BHW) between k_red2 and k_mask (R7-proven).
// Winner keys are chunk-LOCAL u16: global n = chunk*HWC + key - 1; any
// nonzero key in a higher chunk beats all lower chunks — exact LWW merge.

__device__ __forceinline__ void computeP(const float* __restrict__ Kb,
                                         const float* __restrict__ Po, float* P) {
#pragma unroll
    for (int i = 0; i < 3; ++i)
#pragma unroll
        for (int j = 0; j < 4; ++j) {
            float s = Kb[i*4+0] * Po[0*4+j];
            s = s + Kb[i*4+1] * Po[1*4+j];
            s = s + Kb[i*4+2] * Po[2*4+j];
            s = s + Kb[i*4+3] * Po[3*4+j];
            P[i*4+j] = s;
        }
}

__device__ __forceinline__ void static_flow_P(
    const float* __restrict__ iK, const float* __restrict__ P,
    int x, int y, float d, float& sx, float& sy)
{
    float fx = (float)x, fy = (float)y;
    float cam0 = iK[0]*fx + iK[1]*fy + iK[2];
    float cam1 = iK[4]*fx + iK[5]*fy + iK[6];
    float cam2 = iK[8]*fx + iK[9]*fy + iK[10];
    cam0 = d * cam0; cam1 = d * cam1; cam2 = d * cam2;
    float cp0 = P[0]*cam0 + P[1]*cam1 + P[2]*cam2  + P[3];
    float cp1 = P[4]*cam0 + P[5]*cam1 + P[6]*cam2  + P[7];
    float cp2 = P[8]*cam0 + P[9]*cam1 + P[10]*cam2 + P[11];
    float pz = cp2 + EPS;
    sx = cp0 / pz - fx;
    sy = cp1 / pz - fy;
}

__device__ __forceinline__ float norm01(float v, float mn, float mx) {
    return (2.0f * (v - mn)) / (mx - mn) - 1.0f;
}

// Block-wide reduce for 1024-thread blocks (16 waves) + broadcast.
__device__ __forceinline__ void blockRed4(float& a0, float& a1, float& a2, float& a3,
                                          float (*sred)[4], float* bc) {
    for (int off = 32; off; off >>= 1) {
        a0 = fminf(a0, __shfl_down(a0, off, 64));
        a1 = fmaxf(a1, __shfl_down(a1, off, 64));
        a2 = fminf(a2, __shfl_down(a2, off, 64));
        a3 = fmaxf(a3, __shfl_down(a3, off, 64));
    }
    int lane = threadIdx.x & 63, wv = threadIdx.x >> 6;
    if (lane == 0) { sred[wv][0]=a0; sred[wv][1]=a1; sred[wv][2]=a2; sred[wv][3]=a3; }
    __syncthreads();
    if (threadIdx.x == 0) {
#pragma unroll
        for (int w = 1; w < 16; ++w) {
            a0 = fminf(a0, sred[w][0]); a1 = fmaxf(a1, sred[w][1]);
            a2 = fminf(a2, sred[w][2]); a3 = fmaxf(a3, sred[w][3]);
        }
        bc[0]=a0; bc[1]=a1; bc[2]=a2; bc[3]=a3;
    }
    __syncthreads();
    a0=bc[0]; a1=bc[1]; a2=bc[2]; a3=bc[3];
}

__device__ __forceinline__ void blockRed2(float& a0, float& a1,
                                          float (*sred)[4], float* bc) {
    for (int off = 32; off; off >>= 1) {
        a0 = fminf(a0, __shfl_down(a0, off, 64));
        a1 = fmaxf(a1, __shfl_down(a1, off, 64));
    }
    int lane = threadIdx.x & 63, wv = threadIdx.x >> 6;
    if (lane == 0) { sred[wv][0]=a0; sred[wv][1]=a1; }
    __syncthreads();
    if (threadIdx.x == 0) {
#pragma unroll
        for (int w = 1; w < 16; ++w) {
            a0 = fminf(a0, sred[w][0]); a1 = fmaxf(a1, sred[w][1]);
        }
        bc[0]=a0; bc[1]=a1;
    }
    __syncthreads();
    a0=bc[0]; a1=bc[1];
}

// Dispatch 1: winner scan (LDS atomics, chunk-local keys) + flow min/max on
// the same loads + this block's 3840-pixel slice of static-flow min/max.
__global__ void __launch_bounds__(WTPB, 8)
k_winner(const float* __restrict__ flow, const float* __restrict__ depth,
         const float* __restrict__ Km, const float* __restrict__ invK,
         const float* __restrict__ pose,
         unsigned short* __restrict__ partial, float* __restrict__ redA) {
    __shared__ unsigned int win[TRW];   // 61440 B -> 2 blocks/CU
    __shared__ float sred[16][4];
    __shared__ float bc[4];

    const int wg    = blockIdx.x;
    const int chunk = wg & (SC - 1);
    const int bt    = wg >> 2;
    const int b     = bt / TILES;
    const int tile  = bt - b * TILES;
    const int t0    = tile * TR;

    const float* fx_p = flow + b * 2 * HW;
    const float* fy_p = fx_p + HW;

    for (int i = threadIdx.x; i < TRW; i += WTPB) win[i] = 0u;
    __syncthreads();

    float fmn = INFINITY, fmx = -INFINITY, smn = INFINITY, smx = -INFINITY;
    // winner scan over this chunk's sources; flow min/max rides along free.
    const int s_beg = chunk * HWC;
    const int s_end = s_beg + HWC;
    for (int s0 = s_beg + threadIdx.x * 4; s0 < s_end; s0 += WTPB * 4) {
        float4 fx4 = *(const float4*)(fx_p + s0);
        float4 fy4 = *(const float4*)(fy_p + s0);
        fmn = fminf(fmn, fminf(fminf(fx4.x, fx4.y), fminf(fx4.z, fx4.w)));
        fmx = fmaxf(fmx, fmaxf(fmaxf(fx4.x, fx4.y), fmaxf(fx4.z, fx4.w)));
        fmn = fminf(fmn, fminf(fminf(fy4.x, fy4.y), fminf(fy4.z, fy4.w)));
        fmx = fmaxf(fmx, fmaxf(fmaxf(fy4.x, fy4.y), fmaxf(fy4.z, fy4.w)));
        int y = s0 / W;
        int x = s0 - y * W;              // groups never cross a row (W%4==0)
        float fxa[4] = {fx4.x, fx4.y, fx4.z, fx4.w};
        float fya[4] = {fy4.x, fy4.y, fy4.z, fy4.w};
#pragma unroll
        for (int j = 0; j < 4; ++j) {
            int cxi = (int)rintf((float)(x + j) + fxa[j]);
            int cyi = (int)rintf((float)y + fya[j]);
            cxi = min(max(cxi, 0), W - 1);
            cyi = min(max(cyi, 0), H - 1);
            if (cyi >= t0 && cyi < t0 + TR) {
                unsigned key = (unsigned)(s0 + j + 1 - s_beg);  // local, ≤30720
                atomicMax(&win[(cyi - t0) * W + cxi], key);
            }
        }
    }
    __syncthreads();
    {   // partial writeout (coalesced u16)
        unsigned short* dst = partial + (size_t)wg * TRW;
        for (int i = threadIdx.x; i < TRW; i += WTPB)
            dst[i] = (unsigned short)win[i];
    }

    // static-flow min/max over THIS block's distinct 3840-pixel slice
    // (384 blocks exactly tile BHW; rows aligned: SPB % W == 0).
    {
        const float* iK = invK + b * 16;
        float P[12];
        computeP(Km + b * 16, pose + b * 16, P);
        int n0s = chunk * HWC + tile * SPB;
        if (threadIdx.x < SPB / 4) {
            int n = n0s + threadIdx.x * 4;
            int y = n / W;
            int x0 = n - y * W;
            float4 d4 = *(const float4*)(depth + b * HW + n);
            float da[4] = {d4.x, d4.y, d4.z, d4.w};
#pragma unroll
            for (int j = 0; j < 4; ++j) {
                float sx, sy;
                static_flow_P(iK, P, x0 + j, y, da[j], sx, sy);
                smn = fminf(smn, fminf(sx, sy));
                smx = fmaxf(smx, fmaxf(sx, sy));
            }
        }
    }
    blockRed4(fmn, fmx, smn, smx, sred, bc);
    if (threadIdx.x == 0) {
        redA[wg*4+0] = fmn; redA[wg*4+1] = fmx;
        redA[wg*4+2] = smn; redA[wg*4+3] = smx;
    }
}

// Dispatch 2: re-reduce redA (L2-hit) + check pass; stash check into
// out[0..BHW); partials -> redB.
__global__ void __launch_bounds__(RTPB)
k_red2(const float* __restrict__ flow, const float* __restrict__ depth,
       const float* __restrict__ Km, const float* __restrict__ invK,
       const float* __restrict__ pose,
       const float* __restrict__ redA, float* __restrict__ redB,
       float* __restrict__ out) {
    __shared__ float sred[16][4];
    __shared__ float bc[4];

    float gfmn = INFINITY, gfmx = -INFINITY, gsmn = INFINITY, gsmx = -INFINITY;
    for (int i = threadIdx.x; i < NBLK; i += RTPB) {
        gfmn = fminf(gfmn, redA[i*4+0]); gfmx = fmaxf(gfmx, redA[i*4+1]);
        gsmn = fminf(gsmn, redA[i*4+2]); gsmx = fmaxf(gsmx, redA[i*4+3]);
    }
    blockRed4(gfmn, gfmx, gsmn, gsmx, sred, bc);

    float cmn = INFINITY, cmx = -INFINITY;
    int bCur = -1;
    float P[12];
    int stride = gridDim.x * blockDim.x;
    for (int g = blockIdx.x * blockDim.x + threadIdx.x; g < BHW / 4; g += stride) {
        int p0 = g * 4;
        int b  = p0 / HW;
        if (b != bCur) { computeP(Km + b * 16, pose + b * 16, P); bCur = b; }
        const float* iK = invK + b * 16;
        int n0 = p0 - b * HW;
        int y  = n0 / W;
        int x0 = n0 - y * W;
        float4 fx4 = *(const float4*)(flow + b*2*HW + n0);
        float4 fy4 = *(const float4*)(flow + b*2*HW + HW + n0);
        float4 d4  = *(const float4*)(depth + p0);
        float fxa[4] = {fx4.x, fx4.y, fx4.z, fx4.w};
        float fya[4] = {fy4.x, fy4.y, fy4.z, fy4.w};
        float da[4]  = {d4.x, d4.y, d4.z, d4.w};
        float4 cv;
        float* cva = (float*)&cv;
#pragma unroll
        for (int j = 0; j < 4; ++j) {
            float sx, sy;
            static_flow_P(iK, P, x0 + j, y, da[j], sx, sy);
            float dx = norm01(fxa[j], gfmn, gfmx) - norm01(sx, gsmn, gsmx);
            float dy = norm01(fya[j], gfmn, gfmx) - norm01(sy, gsmn, gsmx);
            float c = sqrtf(dx*dx + dy*dy);
            cva[j] = c;
            cmn = fminf(cmn, c); cmx = fmaxf(cmx, c);
        }
        *(float4*)(out + p0) = cv;   // stash check (overwritten by k_mask)
    }
    blockRed2(cmn, cmx, sred, bc);
    if (threadIdx.x == 0) { redB[blockIdx.x*2] = cmn; redB[blockIdx.x*2+1] = cmx; }
}

// Dispatch 3: re-reduce redB + threshold stashed check in-place + winner
// merge (highest nonzero chunk) + exact-payload gathers.
__global__ void __launch_bounds__(RTPB)
k_mask(const float* __restrict__ flow, const int* __restrict__ seg,
       const float* __restrict__ redB, const unsigned short* __restrict__ partial,
       float* __restrict__ out) {
    __shared__ float sred[16][4];
    __shared__ float bc[4];

    float gcmn = INFINITY, gcmx = -INFINITY;
    for (int i = threadIdx.x; i < RBLK; i += RTPB) {
        gcmn = fminf(gcmn, redB[2*i]); gcmx = fmaxf(gcmx, redB[2*i+1]);
    }
    blockRed2(gcmn, gcmx, sred, bc);

    int stride = gridDim.x * blockDim.x;
    for (int p = blockIdx.x * blockDim.x + threadIdx.x; p < BHW; p += stride) {
        float c  = out[p];                    // stashed check
        float cn = (c - gcmn) / (gcmx - gcmn);
        out[p] = (cn < 0.98f) ? 1.0f : 0.0f;

        int b    = p / HW;
        int n    = p - b * HW;
        int tile = n / TRW;
        int off  = n - tile * TRW;
        const unsigned short* base =
            partial + (size_t)(b * TILES + tile) * SC * TRW + off;
        // highest chunk with nonzero key wins (global n = chunk*HWC + key - 1)
        int nw = -1;
#pragma unroll
        for (int cch = 0; cch < SC; ++cch) {
            unsigned k = base[(size_t)cch * TRW];
            if (k) nw = cch * HWC + (int)k - 1;
        }
        float bx = 0.0f, by = 0.0f, sg = 0.0f;
        if (nw >= 0) {
            bx = -flow[b*2*HW + nw];              // exact payload via gather
            by = -flow[b*2*HW + HW + nw];
            sg = seg[b*HW + nw] ? 1.0f : 0.0f;
        }
        out[BHW + b*2*HW + n]      = bx;
        out[BHW + b*2*HW + HW + n] = by;
        out[3*BHW + p]             = sg;
    }
}

} // namespace

extern "C" void kernel_launch(void* const* d_in, const int* in_sizes, int n_in,
                              void* d_out, int out_size, void* d_ws, size_t ws_size,
                              hipStream_t stream) {
    const float* flow  = (const float*)d_in[0];
    const float* depth = (const float*)d_in[1];
    const float* Km    = (const float*)d_in[2];
    const float* invK  = (const float*)d_in[3];
    const float* pose  = (const float*)d_in[4];
    const int*   seg   = (const int*)d_in[5];
    float* out = (float*)d_out;

    float* redA = (float*)d_ws;
    float* redB = (float*)((char*)d_ws + 8192);
    unsigned short* partial = (unsigned short*)((char*)d_ws + 16384);  // 11.8 MB

    k_winner<<<NBLK, WTPB, 0, stream>>>(flow, depth, Km, invK, pose, partial, redA);
    k_red2  <<<RBLK, RTPB, 0, stream>>>(flow, depth, Km, invK, pose, redA, redB, out);
    k_mask  <<<RBLK, RTPB, 0, stream>>>(flow, seg, redB, partial, out);
}